// Round 12
// baseline (48.783 us; speedup 1.0000x reference)
//
#include <hip/hip_runtime.h>
#include <math.h>

// ListNet segment-softmax CE, sorted week indices.
// BATCH = 4194304, NUM_WEEKS = 262144, avg 16 items/week.
//
// Per-week loss = T/S_l - log(S_s);  S_l = sum e^l, S_s = sum e^s, T = sum e^l*s.
// (eps inside log dropped; validated rounds 2-11, absmax 0.0)
//
// Round-12: NO LDS, NO ATOMICS in the main pass. Cross-round evidence
// (r3/r5/r6/r7/r9: dur monotone in LDS-atomic lane-ops/item at ~25us per
// op/item, anti-correlated with load quality) implicates the flush atomics.
// So: thread-interior runs finalize in registers (complete weeks); each
// thread's <=2 boundary runs go to GLOBAL records at deterministic indices
// (coalesced int2/float2 stores, filler record keeps week-adjacency);
// per-wave loss partials stored by lane 0. merge_records (128 blocks)
// run-merges the week-sorted records + sums partials into per-block doubles;
// write_result (1 block) folds 128 partials into the scalar.

#define TPB 256
#define K 16
#define CHUNK (TPB * K)   // 4096 items per block

__global__ __launch_bounds__(TPB) void mainpass_nolds(
        const float* __restrict__ scores, const float* __restrict__ labels,
        const int* __restrict__ widx,
        int* __restrict__ rec_week, float* __restrict__ rec_el,
        float* __restrict__ rec_es, float* __restrict__ rec_tl,
        int* __restrict__ rec_cnt,
        float* __restrict__ wave_loss, int* __restrict__ wave_nv) {
    const int tid = threadIdx.x;
    const int gtid = blockIdx.x * TPB + tid;
    const int t0 = gtid * K;

    const int4   wA = *reinterpret_cast<const int4*>(widx + t0);
    const int4   wB = *reinterpret_cast<const int4*>(widx + t0 + 4);
    const int4   wC = *reinterpret_cast<const int4*>(widx + t0 + 8);
    const int4   wD = *reinterpret_cast<const int4*>(widx + t0 + 12);
    const float4 lA = *reinterpret_cast<const float4*>(labels + t0);
    const float4 lB = *reinterpret_cast<const float4*>(labels + t0 + 4);
    const float4 lC = *reinterpret_cast<const float4*>(labels + t0 + 8);
    const float4 lD = *reinterpret_cast<const float4*>(labels + t0 + 12);
    const float4 sA = *reinterpret_cast<const float4*>(scores + t0);
    const float4 sB = *reinterpret_cast<const float4*>(scores + t0 + 4);
    const float4 sC = *reinterpret_cast<const float4*>(scores + t0 + 8);
    const float4 sD = *reinterpret_cast<const float4*>(scores + t0 + 12);

    float loss = 0.f; int nv = 0;
    // current run
    int cw; float ra, rb, rt; int rc;
    // saved head-boundary run
    bool head_saved = false;
    int hw = 0; float ha = 0.f, hb = 0.f, ht = 0.f; int hc = 0;
    {
        const float el = __expf(lA.x), es = __expf(sA.x);
        cw = wA.x; ra = el; rb = es; rt = el * sA.x; rc = 1;
    }
#define ITEM(wv_, lv_, sv_)                                                    \
    {                                                                          \
        const float el = __expf(lv_), es = __expf(sv_);                        \
        if ((wv_) == cw) { ra += el; rb += es; rt += el * (sv_); ++rc; }       \
        else {                                                                 \
            if (!head_saved) {                                                 \
                hw = cw; ha = ra; hb = rb; ht = rt; hc = rc;                   \
                head_saved = true;                                             \
            } else if (rc >= 2) {  /* run began & ended inside thread */       \
                loss += rt / ra - __logf(rb); ++nv;                            \
            }                                                                  \
            cw = (wv_); ra = el; rb = es; rt = el * (sv_); rc = 1;             \
        }                                                                      \
    }
    ITEM(wA.y, lA.y, sA.y) ITEM(wA.z, lA.z, sA.z) ITEM(wA.w, lA.w, sA.w)
    ITEM(wB.x, lB.x, sB.x) ITEM(wB.y, lB.y, sB.y) ITEM(wB.z, lB.z, sB.z)
    ITEM(wB.w, lB.w, sB.w)
    ITEM(wC.x, lC.x, sC.x) ITEM(wC.y, lC.y, sC.y) ITEM(wC.z, lC.z, sC.z)
    ITEM(wC.w, lC.w, sC.w)
    ITEM(wD.x, lD.x, sD.x) ITEM(wD.y, lD.y, sD.y) ITEM(wD.z, lD.z, sD.z)
    ITEM(wD.w, lD.w, sD.w)
#undef ITEM

    // emit boundary records [head, tail]; single-run thread -> zero filler
    // with the same week (keeps week-run adjacency intact for the merge)
    if (!head_saved) { hw = cw; ha = 0.f; hb = 0.f; ht = 0.f; hc = 0; }
    reinterpret_cast<int2*>(rec_week)[gtid]  = make_int2(hw, cw);
    reinterpret_cast<float2*>(rec_el)[gtid]  = make_float2(ha, ra);
    reinterpret_cast<float2*>(rec_es)[gtid]  = make_float2(hb, rb);
    reinterpret_cast<float2*>(rec_tl)[gtid]  = make_float2(ht, rt);
    reinterpret_cast<int2*>(rec_cnt)[gtid]   = make_int2(hc, rc);

    // per-wave loss partial (no LDS, no barrier)
    #pragma unroll
    for (int off = 32; off; off >>= 1) {
        loss += __shfl_down(loss, off);
        nv   += __shfl_down(nv, off);
    }
    if ((tid & 63) == 0) {
        wave_loss[gtid >> 6] = loss;
        wave_nv[gtid >> 6]   = nv;
    }
}

#define MBLK 128

__global__ __launch_bounds__(256) void merge_records(
        const int* __restrict__ rec_week, const float* __restrict__ rec_el,
        const float* __restrict__ rec_es, const float* __restrict__ rec_tl,
        const int* __restrict__ rec_cnt,
        const float* __restrict__ wave_loss, const int* __restrict__ wave_nv,
        int nrec, int nwave,
        double* __restrict__ blk_loss, int* __restrict__ blk_nv) {
    const int tid0 = blockIdx.x * blockDim.x + threadIdx.x;
    const int stride = gridDim.x * blockDim.x;
    float loss = 0.f; int nv = 0;
    for (int j = tid0; j < nrec; j += stride) {
        const int w = rec_week[j];
        if (j > 0 && rec_week[j - 1] == w) continue;   // not a run head
        float a = rec_el[j], b = rec_es[j], t = rec_tl[j];
        int c = rec_cnt[j];
        for (int k = j + 1; k < nrec && rec_week[k] == w; ++k) {
            a += rec_el[k]; b += rec_es[k]; t += rec_tl[k]; c += rec_cnt[k];
        }
        if (c >= 2) { loss += t / a - __logf(b); ++nv; }
    }
    for (int j = tid0; j < nwave; j += stride) {
        loss += wave_loss[j]; nv += wave_nv[j];
    }
    double dl = (double)loss;
    #pragma unroll
    for (int off = 32; off; off >>= 1) {
        dl += __shfl_down(dl, off);
        nv += __shfl_down(nv, off);
    }
    __shared__ double sa[4];
    __shared__ int    sn[4];
    const int lane = threadIdx.x & 63, wv = threadIdx.x >> 6;
    if (lane == 0) { sa[wv] = dl; sn[wv] = nv; }
    __syncthreads();
    if (threadIdx.x == 0) {
        blk_loss[blockIdx.x] = sa[0] + sa[1] + sa[2] + sa[3];
        blk_nv[blockIdx.x]   = sn[0] + sn[1] + sn[2] + sn[3];
    }
}

__global__ __launch_bounds__(MBLK) void write_result(
        const double* __restrict__ blk_loss, const int* __restrict__ blk_nv,
        float* __restrict__ out) {
    const int tid = threadIdx.x;
    double dl = blk_loss[tid];
    int    nv = blk_nv[tid];
    #pragma unroll
    for (int off = 32; off; off >>= 1) {
        dl += __shfl_down(dl, off);
        nv += __shfl_down(nv, off);
    }
    __shared__ double sa[2];
    __shared__ int    sn[2];
    if ((tid & 63) == 0) { sa[tid >> 6] = dl; sn[tid >> 6] = nv; }
    __syncthreads();
    if (tid == 0) {
        const double tl = sa[0] + sa[1];
        const int    tn = sn[0] + sn[1];
        out[0] = (tn > 0) ? (float)(-tl / (double)tn) : 0.f;
    }
}

extern "C" void kernel_launch(void* const* d_in, const int* in_sizes, int n_in,
                              void* d_out, int out_size, void* d_ws, size_t ws_size,
                              hipStream_t stream) {
    const float* scores = (const float*)d_in[0];
    const float* labels = (const float*)d_in[1];
    const int*   widx   = (const int*)d_in[2];
    const int n  = in_sizes[0];
    const int nthreads = n / K;        // 262144
    const int nb = nthreads / TPB;     // 1024
    const int nrec = nthreads * 2;     // 524288
    const int nwave = nthreads / 64;   // 4096

    char* ws = (char*)d_ws;
    size_t off = 0;
    int*    rec_week = (int*)   (ws + off); off += (size_t)nrec * 4;
    float*  rec_el   = (float*) (ws + off); off += (size_t)nrec * 4;
    float*  rec_es   = (float*) (ws + off); off += (size_t)nrec * 4;
    float*  rec_tl   = (float*) (ws + off); off += (size_t)nrec * 4;
    int*    rec_cnt  = (int*)   (ws + off); off += (size_t)nrec * 4;
    float*  wave_loss= (float*) (ws + off); off += (size_t)nwave * 4;
    int*    wave_nv  = (int*)   (ws + off); off += (size_t)nwave * 4;
    double* blk_loss = (double*)(ws + off); off += (size_t)MBLK * 8;
    int*    blk_nv   = (int*)   (ws + off);

    float* out = (float*)d_out;

    mainpass_nolds<<<nb, TPB, 0, stream>>>(scores, labels, widx,
                                           rec_week, rec_el, rec_es, rec_tl,
                                           rec_cnt, wave_loss, wave_nv);
    merge_records<<<MBLK, 256, 0, stream>>>(rec_week, rec_el, rec_es, rec_tl,
                                            rec_cnt, wave_loss, wave_nv,
                                            nrec, nwave, blk_loss, blk_nv);
    write_result<<<1, MBLK, 0, stream>>>(blk_loss, blk_nv, out);
}